// Round 5
// baseline (454.368 us; speedup 1.0000x reference)
//
#include <hip/hip_runtime.h>
#include <hip/hip_bf16.h>
#include <math.h>
#include <stdint.h>

// InfoNCE fused: sim = A @ B^T / T  (8192x8192x512, fp32 in)
// loss = mean_i( logsumexp_j sim[i,j] - sim[i,i] )
// R5: A-frags direct from global (no LDS), B via XOR-swizzled k-major LDS
// (conflict-free), stateless per-tile LSE epilogue, transposed partials.

#define NB 8192
#define DDIM 512
#define SPLITS 16
#define BM 128
#define BN 128
#define BK 32
#define CPB (NB / SPLITS)        // 512 cols per block
#define TPB (CPB / BN)           // 4 col tiles per block
#define NPART (SPLITS * TPB * 2) // 128 (m,l) partials per row

typedef unsigned short u16;
typedef __attribute__((ext_vector_type(8))) short short8;
typedef __attribute__((ext_vector_type(4))) float f32x4;

__device__ __forceinline__ u16 f2bf(float f) {
  unsigned u = __float_as_uint(f);
  u += 0x7FFFu + ((u >> 16) & 1u);   // round-to-nearest-even
  return (u16)(u >> 16);
}

// global -> LDS direct copy, 16B per lane: HW writes ldsbase + lane*16.
__device__ __forceinline__ void gl2lds16(const u16* g, const u16* l) {
  __builtin_amdgcn_global_load_lds(
      (__attribute__((address_space(1))) unsigned int*)(uintptr_t)g,
      (__attribute__((address_space(3))) unsigned int*)(unsigned int)(uintptr_t)l,
      16, 0, 0);
}

// One wave per row: convert a & p rows to bf16, diag dot in fp32; zero out.
__global__ void cvt_diag_kernel(const float* __restrict__ a, const float* __restrict__ p,
                                u16* __restrict__ ab, u16* __restrict__ pb,
                                float* __restrict__ diag, float* __restrict__ out) {
  if (blockIdx.x == 0 && threadIdx.x == 0) out[0] = 0.f;
  int row = (blockIdx.x * 256 + threadIdx.x) >> 6;
  int lane = threadIdx.x & 63;
  const float4* ar = (const float4*)(a + (size_t)row * DDIM + lane * 8);
  const float4* pr = (const float4*)(p + (size_t)row * DDIM + lane * 8);
  float4 a0 = ar[0], a1 = ar[1];
  float4 p0 = pr[0], p1 = pr[1];
  ushort4* abr = (ushort4*)(ab + (size_t)row * DDIM + lane * 8);
  ushort4* pbr = (ushort4*)(pb + (size_t)row * DDIM + lane * 8);
  abr[0] = (ushort4){f2bf(a0.x), f2bf(a0.y), f2bf(a0.z), f2bf(a0.w)};
  abr[1] = (ushort4){f2bf(a1.x), f2bf(a1.y), f2bf(a1.z), f2bf(a1.w)};
  pbr[0] = (ushort4){f2bf(p0.x), f2bf(p0.y), f2bf(p0.z), f2bf(p0.w)};
  pbr[1] = (ushort4){f2bf(p1.x), f2bf(p1.y), f2bf(p1.z), f2bf(p1.w)};
  float s = a0.x * p0.x + a0.y * p0.y + a0.z * p0.z + a0.w * p0.w +
            a1.x * p1.x + a1.y * p1.y + a1.z * p1.z + a1.w * p1.w;
  for (int off = 32; off > 0; off >>= 1) s += __shfl_down(s, off);
  if (lane == 0) diag[row] = s * 10.0f;  // / T
}

__global__ __launch_bounds__(256, 4) void gemm_lse(
    const u16* __restrict__ Abf, const u16* __restrict__ Bbf,
    float* __restrict__ partM, float* __restrict__ partL) {
  // B-only LDS, k-major 16B chunks, XOR-swizzled: chunk(col, q) lives at byte
  // col*64 + (q ^ ((col>>2)&3))*16. Fragment reads: 2-way bank alias = free.
  __shared__ u16 sB[BN * BK];   // 8 KB

  const int tid = threadIdx.x;
  const int wave = tid >> 6;
  const int lane = tid & 63;
  const int quad = lane >> 4;
  const int l16 = lane & 15;
  const int wr = wave >> 1, wc = wave & 1;  // 2x2 wave grid, each 64x64

  const int row0 = blockIdx.x * BM;
  const int col0 = blockIdx.y * CPB;

  // --- B staging source mapping (inverse of the LDS swizzle) ---
  // Wave w, load j stages linear chunks n = (w*2+j)*64 + lane.
  // col = n>>2, stored k-octet q = (n&3) ^ ((col>>2)&3).
  const int n0 = wave * 128 + lane;          // j = 0
  const int n1 = n0 + 64;                    // j = 1
  const int colS0 = n0 >> 2, qS0 = (n0 & 3) ^ ((colS0 >> 2) & 3);
  const int colS1 = n1 >> 2, qS1 = (n1 & 3) ^ ((colS1 >> 2) & 3);
  const u16* ldsB0 = &sB[wave * 1024];
  const u16* ldsB1 = &sB[wave * 1024 + 512];

  // --- A direct-from-global fragment pointers (16B contiguous per lane) ---
  const u16* aBase[4];
#pragma unroll
  for (int mi = 0; mi < 4; ++mi)
    aBase[mi] = Abf + (size_t)(row0 + wr * 64 + mi * 16 + l16) * DDIM + quad * 8;

  // --- B fragment LDS read base: col = wc*64 + ni*16 + l16, swizzle by l16>>2
  const int sw = quad ^ (l16 >> 2);
  const u16* pbBase = &sB[(wc * 64 + l16) * 32 + sw * 8];

  for (int t = 0; t < TPB; ++t) {
    const u16* bT0 = Bbf + (size_t)(col0 + t * BN + colS0) * DDIM + qS0 * 8;
    const u16* bT1 = Bbf + (size_t)(col0 + t * BN + colS1) * DDIM + qS1 * 8;

    f32x4 acc[4][4];
#pragma unroll
    for (int mi = 0; mi < 4; ++mi)
#pragma unroll
      for (int ni = 0; ni < 4; ++ni) acc[mi][ni] = (f32x4){0.f, 0.f, 0.f, 0.f};

    for (int kk = 0; kk < DDIM; kk += BK) {
      __syncthreads();  // previous step's B readers done
      gl2lds16(bT0 + kk, ldsB0);
      gl2lds16(bT1 + kk, ldsB1);
      short8 af[4];
#pragma unroll
      for (int mi = 0; mi < 4; ++mi)
        af[mi] = *(const short8*)(aBase[mi] + kk);  // global, drained by barrier
      __syncthreads();  // B staged (vmcnt(0) drain covers af too)

      short8 bq[4];
#pragma unroll
      for (int ni = 0; ni < 4; ++ni)
        bq[ni] = *(const short8*)(pbBase + ni * 512);
#pragma unroll
      for (int mi = 0; mi < 4; ++mi)
#pragma unroll
        for (int ni = 0; ni < 4; ++ni)
          acc[mi][ni] =
              __builtin_amdgcn_mfma_f32_16x16x32_bf16(af[mi], bq[ni], acc[mi][ni], 0, 0, 0);
    }

    // Stateless per-tile LSE: shfl-merge over the 16 l16 lanes (64 cols),
    // lane l16==0 writes this tile's (m,l) to transposed partials [row][p].
    const int p = (blockIdx.y * TPB + t) * 2 + wc;
#pragma unroll
    for (int mi = 0; mi < 4; ++mi) {
#pragma unroll
      for (int r = 0; r < 4; ++r) {
        float v0 = acc[mi][0][r] * 10.0f;  // apply 1/T
        float v1 = acc[mi][1][r] * 10.0f;
        float v2 = acc[mi][2][r] * 10.0f;
        float v3 = acc[mi][3][r] * 10.0f;
        float mx = fmaxf(fmaxf(v0, v1), fmaxf(v2, v3));
        mx = fmaxf(mx, __shfl_xor(mx, 1));
        mx = fmaxf(mx, __shfl_xor(mx, 2));
        mx = fmaxf(mx, __shfl_xor(mx, 4));
        mx = fmaxf(mx, __shfl_xor(mx, 8));
        float s = __expf(v0 - mx) + __expf(v1 - mx) + __expf(v2 - mx) + __expf(v3 - mx);
        s += __shfl_xor(s, 1);
        s += __shfl_xor(s, 2);
        s += __shfl_xor(s, 4);
        s += __shfl_xor(s, 8);
        if (l16 == 0) {
          int row = row0 + wr * 64 + mi * 16 + quad * 4 + r;
          partM[(size_t)row * NPART + p] = mx;
          partL[(size_t)row * NPART + p] = s;
        }
      }
    }
  }
}

// One wave per row (8 rows per wave): merge 128 (m,l) partials, subtract diag,
// accumulate mean via one atomic per block.
__global__ void reduce_kernel(const float* __restrict__ partM,
                              const float* __restrict__ partL,
                              const float* __restrict__ diag, float* __restrict__ out) {
  __shared__ float red[4];
  const int wave = threadIdx.x >> 6;
  const int lane = threadIdx.x & 63;
  float vsum = 0.f;
  for (int i = 0; i < 8; ++i) {
    int row = blockIdx.x * 32 + wave * 8 + i;
    float m0 = partM[(size_t)row * NPART + lane];
    float l0 = partL[(size_t)row * NPART + lane];
    float m1 = partM[(size_t)row * NPART + 64 + lane];
    float l1 = partL[(size_t)row * NPART + 64 + lane];
    float m = fmaxf(m0, m1);
    float l = l0 * __expf(m0 - m) + l1 * __expf(m1 - m);
#pragma unroll
    for (int mask = 1; mask < 64; mask <<= 1) {
      float om = __shfl_xor(m, mask);
      float ol = __shfl_xor(l, mask);
      float nm = fmaxf(m, om);
      l = l * __expf(m - nm) + ol * __expf(om - nm);
      m = nm;
    }
    vsum += m + __logf(l) - diag[row];
  }
  if (lane == 0) red[wave] = vsum;
  __syncthreads();
  if (threadIdx.x == 0) {
    float s = (red[0] + red[1] + red[2] + red[3]) * (1.0f / (float)NB);
    atomicAdd(out, s);
  }
}

extern "C" void kernel_launch(void* const* d_in, const int* in_sizes, int n_in,
                              void* d_out, int out_size, void* d_ws, size_t ws_size,
                              hipStream_t stream) {
  const float* anchor = (const float*)d_in[0];
  const float* positive = (const float*)d_in[1];
  float* out = (float*)d_out;

  char* ws = (char*)d_ws;
  u16* Abf = (u16*)ws;                                   // 8 MB
  u16* Bbf = (u16*)(ws + (size_t)8388608);               // 8 MB
  float* diag = (float*)(ws + (size_t)16777216);         // 32 KB
  float* partM = (float*)(ws + (size_t)16777216 + 32768);            // 4 MB
  float* partL = (float*)(ws + (size_t)16777216 + 32768 + (size_t)NPART * NB * 4);

  cvt_diag_kernel<<<NB / 4, 256, 0, stream>>>(anchor, positive, Abf, Bbf, diag, out);
  gemm_lse<<<dim3(NB / BM, SPLITS), 256, 0, stream>>>(Abf, Bbf, partM, partL);
  reduce_kernel<<<NB / 32, 256, 0, stream>>>(partM, partL, diag, out);
}

// Round 6
// 227.657 us; speedup vs baseline: 1.9958x; 1.9958x over previous
//
#include <hip/hip_runtime.h>
#include <hip/hip_bf16.h>
#include <math.h>
#include <stdint.h>

// InfoNCE fused: sim = A @ B^T / T  (8192x8192x512, fp32 in)
// loss = mean_i( logsumexp_j sim[i,j] - sim[i,i] )
// R6: BK=64 (half the barriers), XOR-swizzled LDS (conflict-free reads),
// XCD-aware block remap, stateless per-tile LSE epilogue.

#define NB 8192
#define DDIM 512
#define SPLITS 16
#define BM 128
#define BN 128
#define BK 64
#define CPB (NB / SPLITS)        // 512 cols per block
#define TPB (CPB / BN)           // 4 col tiles per block
#define NPART (SPLITS * TPB * 2) // 128 (m,l) partials per row

typedef unsigned short u16;
typedef __attribute__((ext_vector_type(8))) short short8;
typedef __attribute__((ext_vector_type(4))) float f32x4;

__device__ __forceinline__ u16 f2bf(float f) {
  unsigned u = __float_as_uint(f);
  u += 0x7FFFu + ((u >> 16) & 1u);   // round-to-nearest-even
  return (u16)(u >> 16);
}

// global -> LDS direct copy, 16B per lane: HW writes ldsbase + lane*16.
__device__ __forceinline__ void gl2lds16(const u16* g, const u16* l) {
  __builtin_amdgcn_global_load_lds(
      (__attribute__((address_space(1))) unsigned int*)(uintptr_t)g,
      (__attribute__((address_space(3))) unsigned int*)(unsigned int)(uintptr_t)l,
      16, 0, 0);
}

// One wave per row: convert a & p rows to bf16, diag dot in fp32; zero out.
__global__ void cvt_diag_kernel(const float* __restrict__ a, const float* __restrict__ p,
                                u16* __restrict__ ab, u16* __restrict__ pb,
                                float* __restrict__ diag, float* __restrict__ out) {
  if (blockIdx.x == 0 && threadIdx.x == 0) out[0] = 0.f;
  int row = (blockIdx.x * 256 + threadIdx.x) >> 6;
  int lane = threadIdx.x & 63;
  const float4* ar = (const float4*)(a + (size_t)row * DDIM + lane * 8);
  const float4* pr = (const float4*)(p + (size_t)row * DDIM + lane * 8);
  float4 a0 = ar[0], a1 = ar[1];
  float4 p0 = pr[0], p1 = pr[1];
  ushort4* abr = (ushort4*)(ab + (size_t)row * DDIM + lane * 8);
  ushort4* pbr = (ushort4*)(pb + (size_t)row * DDIM + lane * 8);
  abr[0] = (ushort4){f2bf(a0.x), f2bf(a0.y), f2bf(a0.z), f2bf(a0.w)};
  abr[1] = (ushort4){f2bf(a1.x), f2bf(a1.y), f2bf(a1.z), f2bf(a1.w)};
  pbr[0] = (ushort4){f2bf(p0.x), f2bf(p0.y), f2bf(p0.z), f2bf(p0.w)};
  pbr[1] = (ushort4){f2bf(p1.x), f2bf(p1.y), f2bf(p1.z), f2bf(p1.w)};
  float s = a0.x * p0.x + a0.y * p0.y + a0.z * p0.z + a0.w * p0.w +
            a1.x * p1.x + a1.y * p1.y + a1.z * p1.z + a1.w * p1.w;
  for (int off = 32; off > 0; off >>= 1) s += __shfl_down(s, off);
  if (lane == 0) diag[row] = s * 10.0f;  // / T
}

__global__ __launch_bounds__(256, 4) void gemm_lse(
    const u16* __restrict__ Abf, const u16* __restrict__ Bbf,
    float* __restrict__ partM, float* __restrict__ partL) {
  // LDS row-major [row][64k], 128B rows, XOR swizzle: 16B octet q of row r
  // stored at octet position q ^ (r&7). Fragment reads spread all 32 banks.
  __shared__ u16 sA[BM * BK];   // 16 KB
  __shared__ u16 sB[BN * BK];   // 16 KB

  const int tid = threadIdx.x;
  const int wave = tid >> 6;
  const int lane = tid & 63;
  const int quad = lane >> 4;
  const int l16 = lane & 15;
  const int wr = wave >> 1, wc = wave & 1;  // 2x2 wave grid, each 64x64

  // XCD-aware remap: xcd = bid&7 gets row-tiles {xcd, xcd+8, ..} -> per-XCD
  // A footprint = 1MB (L2-resident); col split varies slowest.
  const int bid = blockIdx.y * 64 + blockIdx.x;
  const int xcd = bid & 7;
  const int idx = bid >> 3;                 // 0..127
  const int rowTile = (idx & 7) * 8 + xcd;  // 0..63
  const int colSplit = idx >> 3;            // 0..15
  const int row0 = rowTile * BM;
  const int col0 = colSplit * CPB;

  // Staging: chunk c = wave*4+j covers rows c*8..c*8+7. Lane covers row
  // c*8 + (lane>>3), stored octet p = lane&7 -> source octet q = p ^ (r&7).
  const int rsub = lane >> 3;                      // 0..7
  const int qsrc = (lane & 7) ^ rsub;              // source k-octet
  const u16* aBase[4];
  const u16* ldsA[4];
  const u16* ldsB[4];
#pragma unroll
  for (int j = 0; j < 4; ++j) {
    int c = wave * 4 + j;
    aBase[j] = Abf + (size_t)(row0 + c * 8 + rsub) * DDIM + qsrc * 8;
    ldsA[j] = &sA[c * 512];
    ldsB[j] = &sB[c * 512];
  }

  // Fragment read offsets: row = w*64 + mi*16 + l16, k-octet kh*4+quad stored
  // at (kh*4+quad) ^ (l16&7); kh=1 position = kh=0 position ^ 4.
  const int p0 = quad ^ (l16 & 7);
  const u16* paBase = &sA[(wr * 64 + l16) * BK];
  const u16* pbBase = &sB[(wc * 64 + l16) * BK];

  for (int t = 0; t < TPB; ++t) {
    const u16* bBase[4];
#pragma unroll
    for (int j = 0; j < 4; ++j)
      bBase[j] = Bbf + (size_t)(col0 + t * BN + (wave * 4 + j) * 8 + rsub) * DDIM + qsrc * 8;

    f32x4 acc[4][4];
#pragma unroll
    for (int mi = 0; mi < 4; ++mi)
#pragma unroll
      for (int ni = 0; ni < 4; ++ni) acc[mi][ni] = (f32x4){0.f, 0.f, 0.f, 0.f};

    for (int kk = 0; kk < DDIM; kk += BK) {
      __syncthreads();  // previous step's readers done
#pragma unroll
      for (int j = 0; j < 4; ++j) {
        gl2lds16(aBase[j] + kk, ldsA[j]);
        gl2lds16(bBase[j] + kk, ldsB[j]);
      }
      __syncthreads();  // staging complete

#pragma unroll
      for (int kh = 0; kh < 2; ++kh) {
        const int pk = (p0 ^ (kh * 4)) * 8;
        short8 af[4], bq[4];
#pragma unroll
        for (int i = 0; i < 4; ++i) {
          af[i] = *(const short8*)(paBase + i * 16 * BK + pk);
          bq[i] = *(const short8*)(pbBase + i * 16 * BK + pk);
        }
#pragma unroll
        for (int mi = 0; mi < 4; ++mi)
#pragma unroll
          for (int ni = 0; ni < 4; ++ni)
            acc[mi][ni] =
                __builtin_amdgcn_mfma_f32_16x16x32_bf16(af[mi], bq[ni], acc[mi][ni], 0, 0, 0);
      }
    }

    // Stateless per-tile LSE: shfl-merge over 16 l16 lanes (64 cols), lane
    // l16==0 writes this tile's (m,l) partial. Layout [p][row] (coalesced).
    const int p = (colSplit * TPB + t) * 2 + wc;
#pragma unroll
    for (int mi = 0; mi < 4; ++mi) {
#pragma unroll
      for (int r = 0; r < 4; ++r) {
        float v0 = acc[mi][0][r] * 10.0f;  // apply 1/T
        float v1 = acc[mi][1][r] * 10.0f;
        float v2 = acc[mi][2][r] * 10.0f;
        float v3 = acc[mi][3][r] * 10.0f;
        float mx = fmaxf(fmaxf(v0, v1), fmaxf(v2, v3));
        mx = fmaxf(mx, __shfl_xor(mx, 1));
        mx = fmaxf(mx, __shfl_xor(mx, 2));
        mx = fmaxf(mx, __shfl_xor(mx, 4));
        mx = fmaxf(mx, __shfl_xor(mx, 8));
        float s = __expf(v0 - mx) + __expf(v1 - mx) + __expf(v2 - mx) + __expf(v3 - mx);
        s += __shfl_xor(s, 1);
        s += __shfl_xor(s, 2);
        s += __shfl_xor(s, 4);
        s += __shfl_xor(s, 8);
        if (l16 == 0) {
          int row = row0 + wr * 64 + mi * 16 + quad * 4 + r;
          partM[(size_t)p * NB + row] = mx;
          partL[(size_t)p * NB + row] = s;
        }
      }
    }
  }
}

// One row per thread, 32 blocks; block-sum -> atomicAdd.
__global__ void reduce_kernel(const float* __restrict__ partM,
                              const float* __restrict__ partL,
                              const float* __restrict__ diag, float* __restrict__ out) {
  __shared__ float red[4];
  int r = blockIdx.x * 256 + threadIdx.x;
  float M = -INFINITY;
  for (int s = 0; s < NPART; ++s) M = fmaxf(M, partM[(size_t)s * NB + r]);
  float L = 0.f;
  for (int s = 0; s < NPART; ++s)
    L += partL[(size_t)s * NB + r] * __expf(partM[(size_t)s * NB + r] - M);
  float v = M + __logf(L) - diag[r];
  for (int off = 32; off > 0; off >>= 1) v += __shfl_down(v, off);
  if ((threadIdx.x & 63) == 0) red[threadIdx.x >> 6] = v;
  __syncthreads();
  if (threadIdx.x == 0) {
    float s = (red[0] + red[1] + red[2] + red[3]) * (1.0f / (float)NB);
    atomicAdd(out, s);
  }
}

extern "C" void kernel_launch(void* const* d_in, const int* in_sizes, int n_in,
                              void* d_out, int out_size, void* d_ws, size_t ws_size,
                              hipStream_t stream) {
  const float* anchor = (const float*)d_in[0];
  const float* positive = (const float*)d_in[1];
  float* out = (float*)d_out;

  char* ws = (char*)d_ws;
  u16* Abf = (u16*)ws;                                   // 8 MB
  u16* Bbf = (u16*)(ws + (size_t)8388608);               // 8 MB
  float* diag = (float*)(ws + (size_t)16777216);         // 32 KB
  float* partM = (float*)(ws + (size_t)16777216 + 32768);            // 4 MB
  float* partL = (float*)(ws + (size_t)16777216 + 32768 + (size_t)NPART * NB * 4);

  cvt_diag_kernel<<<NB / 4, 256, 0, stream>>>(anchor, positive, Abf, Bbf, diag, out);
  gemm_lse<<<dim3(64, SPLITS), 256, 0, stream>>>(Abf, Bbf, partM, partL);
  reduce_kernel<<<NB / 256, 256, 0, stream>>>(partM, partL, diag, out);
}